// Round 10
// baseline (383.369 us; speedup 1.0000x reference)
//
#include <hip/hip_runtime.h>
#include <hip/hip_bf16.h>

typedef __attribute__((ext_vector_type(4))) float f32x4;
typedef __attribute__((ext_vector_type(8))) short short8;
typedef __attribute__((ext_vector_type(4))) short short4v;
using bf16 = __hip_bfloat16;

__device__ __forceinline__ short f2bf(float x) {
  union { bf16 h; short s; } u;
  u.h = __float2bfloat16(x);
  return u.s;
}

__device__ __forceinline__ void gload16(const void* g, void* l) {
  __builtin_amdgcn_global_load_lds(
      (const __attribute__((address_space(1))) void*)g,
      (__attribute__((address_space(3))) void*)l, 16, 0, 0);
}

// ---------------- fp32 -> bf16 conversion (weights only) ----------------
__global__ void cvt_f32_to_bf16(const float* __restrict__ src,
                                bf16* __restrict__ dst, int n4) {
  int i = blockIdx.x * blockDim.x + threadIdx.x;
  const int stride = gridDim.x * blockDim.x;
  for (; i < n4; i += stride) {
    f32x4 v = ((const f32x4*)src)[i];
    short4v o;
    o[0] = f2bf(v[0]); o[1] = f2bf(v[1]); o[2] = f2bf(v[2]); o[3] = f2bf(v[3]);
    ((short4v*)dst)[i] = o;
  }
}

// ------- 256x128 QKV GEMM, BK=32, 3-buffer rotation, fused A-conversion -----
// qkv = x(fp32) @ w_in^T + b_in, bf16 out. K=512 = 16 K-tiles, fully
// unrolled. 512 threads = 8 waves (4M x 2N), wave tile 64x64, acc[4][4].
// LDS 72 KiB (3 bufs) => 2 blocks/CU.
//
// A-staging is reg-staged fp32->bf16 (replaces the separate cvt_x pass,
// saving its 201 MB HBM round-trip): during tile t each thread
//   (1) converts A(t+2) (4xf32x4 loaded during t-1; a full tile-time old ->
//       no stall) and ds_write_b128's it to the SAME LDS addresses the old
//       gload16 staging produced (dest = wave base + lane*16B, source col
//       pre-swizzled) -> read side unchanged;
//   (2) issues A(t+3)'s 4 global f32x4 loads;
//   (3) gload_lds stages B(t+2).
// Close of tile t (vmcnt retires IN ISSUE ORDER, m135):
//   outstanding newest = A(t+3)x4 + B(t+2)x1 -> s_waitcnt vmcnt(5)
//   guarantees B(t+1) LDS-resident; lgkmcnt(0) publishes A(t+2) ds_writes;
//   s_barrier publishes to the block. Tail: V(1)@13, V(0)@14.
// Buffer rotation (r4/r8-proven): writes at t target buf (t+2)%3 == (t-1)%3,
// whose last reads retired before the close-of-(t-1) barrier.
__global__ __launch_bounds__(512) void gemm_qkv(
    const float* __restrict__ X,         // [65536][512] fp32
    const bf16* __restrict__ B,          // w_in bf16 [1536][512]
    const float* __restrict__ bias,      // b_in [1536]
    bf16* __restrict__ C, int nbx)       // qkv, ldc = 1536
{
  __shared__ __align__(16) bf16 lA[3][256 * 32];
  __shared__ __align__(16) bf16 lB[3][128 * 32];

  const int tid  = threadIdx.x;
  const int lane = tid & 63;
  const int w    = tid >> 6;   // wave 0..7
  const int mr   = w & 3;      // M quarter: rows mr*64..+63
  const int wn   = w >> 2;     // N half:    cols wn*64..+63
  const int l15  = lane & 15;
  const int kg   = lane >> 4;                    // k-slot 0..3
  const int po   = (kg ^ ((l15 >> 1) & 3)) * 8;  // swizzled read col (elems)

  const int nwg = gridDim.x;
  const int dd  = blockIdx.x;
  const int wid = (dd & 7) * (nwg >> 3) + (dd >> 3);  // bijective XCD swizzle
  const size_t bm = (size_t)(wid / nbx) * 256;
  const size_t bn = (size_t)(wid % nbx) * 128;

  // staging geometry (identical to the verified gload16 pair):
  // source row = bm + w*16 + (lane>>2) (+128 for h=1), source col-slot
  // pre-swizzled (lane&3)^((lane>>3)&3); dest = wave base + lane*16B linear.
  const int srow = w * 16 + (lane >> 2);
  const int scol = ((lane & 3) ^ ((lane >> 3) & 3)) * 8;
  const int wofs = w * 512;

  const float* Xb = X + (bm + srow) * 512 + scol;
  const bf16*  Bb = B + (bn + srow) * 512 + scol;

  f32x4 acc[4][4];
#pragma unroll
  for (int i = 0; i < 4; ++i)
#pragma unroll
    for (int j = 0; j < 4; ++j) acc[i][j] = (f32x4)0.f;

  short8 af[4], bq[4];
  f32x4 xr[4];   // in-flight fp32 A sub-tile (h0:lo,hi ; h1:lo,hi)

#define LOADX(kt) do { \
    xr[0] = *(const f32x4*)(Xb + (kt)); \
    xr[1] = *(const f32x4*)(Xb + (kt) + 4); \
    xr[2] = *(const f32x4*)(Xb + 128 * 512 + (kt)); \
    xr[3] = *(const f32x4*)(Xb + 128 * 512 + (kt) + 4); } while (0)

#define CVTW(buf) do { \
    short8 p0, p1; \
    p0[0] = f2bf(xr[0][0]); p0[1] = f2bf(xr[0][1]); \
    p0[2] = f2bf(xr[0][2]); p0[3] = f2bf(xr[0][3]); \
    p0[4] = f2bf(xr[1][0]); p0[5] = f2bf(xr[1][1]); \
    p0[6] = f2bf(xr[1][2]); p0[7] = f2bf(xr[1][3]); \
    p1[0] = f2bf(xr[2][0]); p1[1] = f2bf(xr[2][1]); \
    p1[2] = f2bf(xr[2][2]); p1[3] = f2bf(xr[2][3]); \
    p1[4] = f2bf(xr[3][0]); p1[5] = f2bf(xr[3][1]); \
    p1[6] = f2bf(xr[3][2]); p1[7] = f2bf(xr[3][3]); \
    *(short8*)&lA[buf][wofs + lane * 8] = p0; \
    *(short8*)&lA[buf][4096 + wofs + lane * 8] = p1; } while (0)

#define STGB(buf, kt) gload16(Bb + (size_t)(kt), &lB[buf][wofs])

#define CLOSE_VL(N) do { \
    __builtin_amdgcn_sched_barrier(0); \
    asm volatile("s_waitcnt vmcnt(" #N ") lgkmcnt(0)" ::: "memory"); \
    __builtin_amdgcn_sched_barrier(0); \
    __builtin_amdgcn_s_barrier(); \
    __builtin_amdgcn_sched_barrier(0); \
    asm volatile("" ::: "memory"); } while (0)

  // prologue: A0,A1 converted+written; B0,B1 staged; A2 loads in flight.
  LOADX(0);  CVTW(0);
  LOADX(32); CVTW(1);
  STGB(0, 0); STGB(1, 32);
  LOADX(64);
  CLOSE_VL(4);   // outstanding: A2 x4; retires B0,B1; publishes A0,A1 writes

#pragma unroll
  for (int t = 0; t < 16; ++t) {
    const int cur = t % 3;
    const int pf  = (t + 2) % 3;

    // fragment reads from the stable current buffer (8 x ds_read_b128)
#pragma unroll
    for (int mi = 0; mi < 4; ++mi)
      af[mi] = *(const short8*)&lA[cur][(mr * 64 + mi * 16 + l15) * 32 + po];
#pragma unroll
    for (int ni = 0; ni < 4; ++ni)
      bq[ni] = *(const short8*)&lB[cur][(wn * 64 + ni * 16 + l15) * 32 + po];

    // stage tile t+2 / issue A(t+3) (buf pf last read during t-1)
    if (t < 14) CVTW(pf);
    if (t < 13) LOADX((t + 3) * 32);
    if (t < 14) STGB(pf, (t + 2) * 32);

    __builtin_amdgcn_s_setprio(1);
#pragma unroll
    for (int mi = 0; mi < 4; ++mi)
#pragma unroll
      for (int ni = 0; ni < 4; ++ni)
        acc[mi][ni] = __builtin_amdgcn_mfma_f32_16x16x32_bf16(
            bq[ni], af[mi], acc[mi][ni], 0, 0, 0);
    __builtin_amdgcn_s_setprio(0);

    if (t <= 12)      CLOSE_VL(5);
    else if (t == 13) CLOSE_VL(1);
    else if (t == 14) CLOSE_VL(0);
    // t == 15: fall through to epilogue
  }

#undef LOADX
#undef CVTW
#undef STGB
#undef CLOSE_VL

  // Epilogue: lane holds m = bm+mr*64+mi*16+l15, n = bn+wn*64+ni*16+kg*4+j
#pragma unroll
  for (int mi = 0; mi < 4; ++mi) {
    const size_t mrow = bm + mr * 64 + mi * 16 + l15;
#pragma unroll
    for (int ni = 0; ni < 4; ++ni) {
      const int nb = (int)bn + wn * 64 + ni * 16 + kg * 4;
      f32x4 bv = *(const f32x4*)&bias[nb];
      f32x4 r = acc[mi][ni] + bv;
      short4v o;
      o[0] = f2bf(r[0]); o[1] = f2bf(r[1]); o[2] = f2bf(r[2]); o[3] = f2bf(r[3]);
      *(short4v*)(C + mrow * 1536 + nb) = o;
    }
  }
}

// ------------- fused block-attention + output GEMM (r9, passing) -------------
// One block per 64 qkv rows. 512 threads = 8 waves; wave w owns attention
// sub-block blk=w>>1 (16 rows) x heads (w&1)*4..+3, and phase-B cols w*64..+63.
// buf[64][520] (65 KB, +8 pad) holds the V-strip (staged via global_load_lds),
// then ctx overwrites each head's own V columns in-place after that head's PV
// (same-wave in-order LDS => race-free). Phase B: out = ctx @ w_out^T + b_out.
__global__ __launch_bounds__(512) void attn_out_kernel(
    const bf16* __restrict__ qkv, const bf16* __restrict__ woutb,
    const float* __restrict__ b_out, float* __restrict__ out)
{
  __shared__ __align__(16) bf16 buf[64][520];

  const int tid  = threadIdx.x;
  const int w    = tid >> 6;
  const int lane = tid & 63;
  const int l15  = lane & 15;
  const int kg   = lane >> 4;
  const size_t mbase = (size_t)blockIdx.x * 64;
  const int blk = w >> 1;
  const size_t rbase = mbase + blk * 16;

  // ---- stage V strip: wave w stages rows w*8..+7, 1024B per row ----
  {
    const bf16* vsrc = qkv + 1024 + (size_t)lane * 8;
#pragma unroll
    for (int i = 0; i < 8; ++i) {
      const int row = w * 8 + i;
      gload16(vsrc + (mbase + row) * 1536, &buf[row][0]);
    }
  }
  __syncthreads();

  // ---- phase A: attention, 4 heads per wave; ctx overwrites own V ----
#pragma unroll
  for (int hi = 0; hi < 4; ++hi) {
    const int h = (w & 1) * 4 + hi;
    const bf16* qp = qkv + (rbase + l15) * 1536 + h * 64 + kg * 8;
    short8 qf0 = *(const short8*)qp;
    short8 qf1 = *(const short8*)(qp + 32);
    short8 kf0 = *(const short8*)(qp + 512);
    short8 kf1 = *(const short8*)(qp + 544);

    // S[q=l15][k=kg*4+r] via swapped QK^T
    f32x4 st = (f32x4)0.f;
    st = __builtin_amdgcn_mfma_f32_16x16x32_bf16(kf0, qf0, st, 0, 0, 0);
    st = __builtin_amdgcn_mfma_f32_16x16x32_bf16(kf1, qf1, st, 0, 0, 0);

    float s[4];
#pragma unroll
    for (int r = 0; r < 4; ++r) s[r] = st[r] * 0.125f;  // 1/sqrt(64)
    float mx = fmaxf(fmaxf(s[0], s[1]), fmaxf(s[2], s[3]));
    mx = fmaxf(mx, __shfl_xor(mx, 16));
    mx = fmaxf(mx, __shfl_xor(mx, 32));
    float p[4], sum = 0.f;
#pragma unroll
    for (int r = 0; r < 4; ++r) { p[r] = __expf(s[r] - mx); sum += p[r]; }
    sum += __shfl_xor(sum, 16);
    sum += __shfl_xor(sum, 32);
    const float inv = 1.f / sum;

    short4v pf;  // P[q=l15][k=kg*4+r]
#pragma unroll
    for (int r = 0; r < 4; ++r) pf[r] = f2bf(p[r] * inv);

#pragma unroll
    for (int dt = 0; dt < 4; ++dt) {
      short4v vf;  // lane holds V[k=kg*4+jj][d=dt*16+l15]
#pragma unroll
      for (int jj = 0; jj < 4; ++jj)
        vf[jj] = *(const short*)&buf[blk * 16 + kg * 4 + jj][h * 64 + dt * 16 + l15];
      // swapped PV: lane holds ctx[q=l15][d = dt*16 + kg*4 + r]
      f32x4 c = (f32x4)0.f;
      c = __builtin_amdgcn_mfma_f32_16x16x16bf16_1k(vf, pf, c, 0, 0, 0);
      short4v o;
#pragma unroll
      for (int r = 0; r < 4; ++r) o[r] = f2bf(c[r]);
      *(short4v*)&buf[blk * 16 + l15][h * 64 + dt * 16 + kg * 4] = o;
    }
  }

  __syncthreads();

  // ---- phase B: out = ctx @ w_out^T + b_out ----
  f32x4 acc[4][4];
#pragma unroll
  for (int i = 0; i < 4; ++i)
#pragma unroll
    for (int j = 0; j < 4; ++j) acc[i][j] = (f32x4)0.f;

#pragma unroll
  for (int kc = 0; kc < 16; ++kc) {
    short8 wf[4], cf[4];
#pragma unroll
    for (int ni = 0; ni < 4; ++ni)
      wf[ni] = *(const short8*)&woutb[(size_t)(w * 64 + ni * 16 + l15) * 512 +
                                      kc * 32 + kg * 8];
#pragma unroll
    for (int mi = 0; mi < 4; ++mi)
      cf[mi] = *(const short8*)&buf[mi * 16 + l15][kc * 32 + kg * 8];
#pragma unroll
    for (int mi = 0; mi < 4; ++mi)
#pragma unroll
      for (int ni = 0; ni < 4; ++ni)
        acc[mi][ni] = __builtin_amdgcn_mfma_f32_16x16x32_bf16(
            wf[ni], cf[mi], acc[mi][ni], 0, 0, 0);
  }

  // epilogue: m = mbase + mi*16 + l15, n = w*64 + ni*16 + kg*4 (+r)
#pragma unroll
  for (int mi = 0; mi < 4; ++mi) {
    const size_t mrow = mbase + mi * 16 + l15;
#pragma unroll
    for (int ni = 0; ni < 4; ++ni) {
      const int nb = w * 64 + ni * 16 + kg * 4;
      f32x4 bv = *(const f32x4*)&b_out[nb];
      *(f32x4*)&out[mrow * 512 + nb] = acc[mi][ni] + bv;
    }
  }
}

// ---------------- launch ----------------
extern "C" void kernel_launch(void* const* d_in, const int* in_sizes, int n_in,
                              void* d_out, int out_size, void* d_ws, size_t ws_size,
                              hipStream_t stream) {
  (void)in_sizes; (void)n_in; (void)out_size; (void)ws_size;
  const float* x     = (const float*)d_in[0];
  const float* w_in  = (const float*)d_in[1];
  const float* b_in  = (const float*)d_in[2];
  const float* w_out = (const float*)d_in[3];
  const float* b_out = (const float*)d_in[4];
  float* out = (float*)d_out;

  char* ws = (char*)d_ws;
  bf16* qkv   = (bf16*)ws;                                   // 65536*1536 bf16 = 201 MB
  bf16* winb  = (bf16*)(ws + (size_t)65536 * 1536 * 2);      // 1536*512
  bf16* woutb = (bf16*)(ws + (size_t)65536 * 1536 * 2 + (size_t)786432 * 2);

  cvt_f32_to_bf16<<<768, 256, 0, stream>>>(w_in, winb, 786432 / 4);
  cvt_f32_to_bf16<<<256, 256, 0, stream>>>(w_out, woutb, 262144 / 4);

  // QKV = x @ w_in^T + b_in  (M=65536, N=1536, K=512), fused fp32->bf16 A
  gemm_qkv<<<3072, 512, 0, stream>>>(x, winb, b_in, qkv, 12);

  // fused: block attention + out = ctx @ w_out^T + b_out (fp32)
  attn_out_kernel<<<1024, 512, 0, stream>>>(qkv, woutb, b_out, out);
}

// Round 11
// 339.062 us; speedup vs baseline: 1.1307x; 1.1307x over previous
//
#include <hip/hip_runtime.h>
#include <hip/hip_bf16.h>

typedef __attribute__((ext_vector_type(4))) float f32x4;
typedef __attribute__((ext_vector_type(8))) short short8;
typedef __attribute__((ext_vector_type(4))) short short4v;
using bf16 = __hip_bfloat16;

__device__ __forceinline__ short f2bf(float x) {
  union { bf16 h; short s; } u;
  u.h = __float2bfloat16(x);
  return u.s;
}

__device__ __forceinline__ void gload16(const void* g, void* l) {
  __builtin_amdgcn_global_load_lds(
      (const __attribute__((address_space(1))) void*)g,
      (__attribute__((address_space(3))) void*)l, 16, 0, 0);
}

// ---------------- fp32 -> bf16 conversion (grid-stride) ----------------
__global__ void cvt_f32_to_bf16(const float* __restrict__ src,
                                bf16* __restrict__ dst, int n4) {
  int i = blockIdx.x * blockDim.x + threadIdx.x;
  const int stride = gridDim.x * blockDim.x;
  for (; i < n4; i += stride) {
    f32x4 v = ((const f32x4*)src)[i];
    short4v o;
    o[0] = f2bf(v[0]); o[1] = f2bf(v[1]); o[2] = f2bf(v[2]); o[3] = f2bf(v[3]);
    ((short4v*)dst)[i] = o;
  }
}

// ------- w_in fp32 -> bf16, packed fragment-major for direct L2 reads -------
// W2 layout (short8 units): [nblk 0..95][kc 0..15][lane 0..63] where
// lane = kg*16 + l15 holds w_in[nblk*16 + l15][kc*32 + kg*8 .. +8).
// A wave's B-fragment load = one coalesced 1KB global_load_dwordx4.
__global__ void cvt_w_pack(const float* __restrict__ w_in,
                           bf16* __restrict__ W2) {
  const int i = blockIdx.x * blockDim.x + threadIdx.x;  // 1536*64 slots
  const int n  = i >> 6;          // row 0..1535
  const int k8 = i & 63;          // 8-elem col slot 0..63
  const int kc = k8 >> 2, kg = k8 & 3, nblk = n >> 4, l15 = n & 15;
  const float* s = w_in + (size_t)n * 512 + k8 * 8;
  f32x4 v0 = *(const f32x4*)s;
  f32x4 v1 = *(const f32x4*)(s + 4);
  short8 o;
  o[0] = f2bf(v0[0]); o[1] = f2bf(v0[1]); o[2] = f2bf(v0[2]); o[3] = f2bf(v0[3]);
  o[4] = f2bf(v1[0]); o[5] = f2bf(v1[1]); o[6] = f2bf(v1[2]); o[7] = f2bf(v1[3]);
  ((short8*)W2)[((size_t)nblk * 16 + kc) * 64 + kg * 16 + l15] = o;
}

// ------- 256x128 QKV GEMM, BK=32: A via LDS, B direct-from-L2 -------
// qkv = xb @ W2^T + b_in. K=512 = 16 K-tiles, fully unrolled. 512 threads =
// 8 waves (4M x 2N), wave tile 64x64, acc[4][4].
//
// LDS-port relief (the 683 TF binder): B fragments come straight from L2
// (W2 packed layout, 4 coalesced 1KB loads/wave/tile, register-dbuf'd one
// tile ahead) -> LDS carries A only (4 ds_read_b128 + 2 gload_lds per wave
// per tile ~540 cyc < 620 cyc MFMA). LDS 48KB (3 bufs) -> 3 blocks/CU.
//
// Ledger: issue order in tile t = [bq(t+1) x4 reg-loads, Astg(t+2) x2].
// Close of t: vmcnt(6) retires A(t+1) stages (older than the 6 newest) ->
// tile t+1's A resident. bq register deps are compiler-tracked. Prologue:
// [bq(0) x4, A0 x2, A1 x2], vmcnt(2) -> bq0+A0 retired, A1 in flight.
// Tail: t=14 issues bq(15) only -> close vmcnt(4); t=15 epilogue.
// A-buf rotation (r8-proven): write (t+2)%3 == (t-1)%3, last read t-1.
__global__ __launch_bounds__(512) void gemm_qkv(
    const bf16* __restrict__ A,          // xb [65536][512]
    const bf16* __restrict__ W2,         // packed w_in
    const float* __restrict__ bias,
    bf16* __restrict__ C, int nbx)       // qkv, ldc = 1536
{
  __shared__ __align__(16) bf16 lA[3][256 * 32];

  const int tid  = threadIdx.x;
  const int lane = tid & 63;
  const int w    = tid >> 6;   // wave 0..7
  const int mr   = w & 3;      // M quarter: rows mr*64..+63
  const int wn   = w >> 2;     // N half:    cols wn*64..+63
  const int l15  = lane & 15;
  const int kg   = lane >> 4;                    // k-slot 0..3
  const int po   = (kg ^ ((l15 >> 1) & 3)) * 8;  // swizzled read col (elems)

  const int nwg = gridDim.x;
  const int dd  = blockIdx.x;
  const int wid = (dd & 7) * (nwg >> 3) + (dd >> 3);  // bijective XCD swizzle
  const size_t bm = (size_t)(wid / nbx) * 256;
  const size_t bn = (size_t)(wid % nbx) * 128;

  const int srow = w * 16 + (lane >> 2);
  const int scol = ((lane & 3) ^ ((lane >> 3) & 3)) * 8;
  const int wofs = w * 512;

  const bf16* Ab = A + (bm + srow) * 512 + scol;
  // per-ni fragment base: W2 short index ((nblk)*16 + t)*512 + lane*8,
  // nblk = bn/16 + wn*4 + ni  ->  base + ni*8192 + t*512
  const bf16* Wb = W2 + (((size_t)(bn >> 4) + wn * 4) * 16) * 512 + lane * 8;

  f32x4 acc[4][4];
#pragma unroll
  for (int i = 0; i < 4; ++i)
#pragma unroll
    for (int j = 0; j < 4; ++j) acc[i][j] = (f32x4)0.f;

  short8 af[4], bqs[2][4];

#define STGA(buf, kt) do { \
    gload16(Ab + (size_t)(kt),            &lA[buf][wofs]); \
    gload16(Ab + (size_t)128 * 512 + (kt), &lA[buf][4096 + wofs]); } while (0)

#define LDB(s, t) do { _Pragma("unroll") for (int ni = 0; ni < 4; ++ni) \
    bqs[s][ni] = *(const short8*)(Wb + ni * 8192 + (t) * 512); } while (0)

#define CLOSE_V(N) do { \
    __builtin_amdgcn_sched_barrier(0); \
    asm volatile("s_waitcnt vmcnt(" #N ")" ::: "memory"); \
    __builtin_amdgcn_sched_barrier(0); \
    __builtin_amdgcn_s_barrier(); \
    __builtin_amdgcn_sched_barrier(0); \
    asm volatile("" ::: "memory"); } while (0)

  // prologue: bq(0) regs; stage A0, A1. vmcnt(2): bq0+A0 retired, A1 in flight
  LDB(0, 0);
  STGA(0, 0);
  STGA(1, 32);
  CLOSE_V(2);

#pragma unroll
  for (int t = 0; t < 16; ++t) {
    const int cur = t % 3;
    const int pf  = (t + 2) % 3;
    const int cs  = t & 1, ns = cs ^ 1;

    // A fragments from stable current buffer (4 x ds_read_b128)
#pragma unroll
    for (int mi = 0; mi < 4; ++mi)
      af[mi] = *(const short8*)&lA[cur][(mr * 64 + mi * 16 + l15) * 32 + po];

    // B fragments for tile t+1 (register dbuf; L2-hot coalesced loads)
    if (t < 15) LDB(ns, t + 1);
    // stage A(t+2) (buf last read during t-1, barrier-separated)
    if (t < 14) STGA(pf, (t + 2) * 32);

    __builtin_amdgcn_s_setprio(1);
#pragma unroll
    for (int mi = 0; mi < 4; ++mi)
#pragma unroll
      for (int ni = 0; ni < 4; ++ni)
        acc[mi][ni] = __builtin_amdgcn_mfma_f32_16x16x32_bf16(
            bqs[cs][ni], af[mi], acc[mi][ni], 0, 0, 0);
    __builtin_amdgcn_s_setprio(0);

    if (t <= 13)      CLOSE_V(6);
    else if (t == 14) CLOSE_V(4);
    // t == 15: fall through to epilogue
  }

#undef STGA
#undef LDB
#undef CLOSE_V

  // Epilogue: lane holds m = bm+mr*64+mi*16+l15, n = bn+wn*64+ni*16+kg*4+j
#pragma unroll
  for (int mi = 0; mi < 4; ++mi) {
    const size_t mrow = bm + mr * 64 + mi * 16 + l15;
#pragma unroll
    for (int ni = 0; ni < 4; ++ni) {
      const int nb = (int)bn + wn * 64 + ni * 16 + kg * 4;
      f32x4 bv = *(const f32x4*)&bias[nb];
      f32x4 r = acc[mi][ni] + bv;
      short4v o;
      o[0] = f2bf(r[0]); o[1] = f2bf(r[1]); o[2] = f2bf(r[2]); o[3] = f2bf(r[3]);
      *(short4v*)(C + mrow * 1536 + nb) = o;
    }
  }
}

// ------------- fused block-attention + output GEMM (r9, passing) -------------
__global__ __launch_bounds__(512) void attn_out_kernel(
    const bf16* __restrict__ qkv, const bf16* __restrict__ woutb,
    const float* __restrict__ b_out, float* __restrict__ out)
{
  __shared__ __align__(16) bf16 buf[64][520];

  const int tid  = threadIdx.x;
  const int w    = tid >> 6;
  const int lane = tid & 63;
  const int l15  = lane & 15;
  const int kg   = lane >> 4;
  const size_t mbase = (size_t)blockIdx.x * 64;
  const int blk = w >> 1;
  const size_t rbase = mbase + blk * 16;

  // ---- stage V strip: wave w stages rows w*8..+7, 1024B per row ----
  {
    const bf16* vsrc = qkv + 1024 + (size_t)lane * 8;
#pragma unroll
    for (int i = 0; i < 8; ++i) {
      const int row = w * 8 + i;
      gload16(vsrc + (mbase + row) * 1536, &buf[row][0]);
    }
  }
  __syncthreads();

  // ---- phase A: attention, 4 heads per wave; ctx overwrites own V ----
#pragma unroll
  for (int hi = 0; hi < 4; ++hi) {
    const int h = (w & 1) * 4 + hi;
    const bf16* qp = qkv + (rbase + l15) * 1536 + h * 64 + kg * 8;
    short8 qf0 = *(const short8*)qp;
    short8 qf1 = *(const short8*)(qp + 32);
    short8 kf0 = *(const short8*)(qp + 512);
    short8 kf1 = *(const short8*)(qp + 544);

    f32x4 st = (f32x4)0.f;
    st = __builtin_amdgcn_mfma_f32_16x16x32_bf16(kf0, qf0, st, 0, 0, 0);
    st = __builtin_amdgcn_mfma_f32_16x16x32_bf16(kf1, qf1, st, 0, 0, 0);

    float s[4];
#pragma unroll
    for (int r = 0; r < 4; ++r) s[r] = st[r] * 0.125f;
    float mx = fmaxf(fmaxf(s[0], s[1]), fmaxf(s[2], s[3]));
    mx = fmaxf(mx, __shfl_xor(mx, 16));
    mx = fmaxf(mx, __shfl_xor(mx, 32));
    float p[4], sum = 0.f;
#pragma unroll
    for (int r = 0; r < 4; ++r) { p[r] = __expf(s[r] - mx); sum += p[r]; }
    sum += __shfl_xor(sum, 16);
    sum += __shfl_xor(sum, 32);
    const float inv = 1.f / sum;

    short4v pf;
#pragma unroll
    for (int r = 0; r < 4; ++r) pf[r] = f2bf(p[r] * inv);

#pragma unroll
    for (int dt = 0; dt < 4; ++dt) {
      short4v vf;
#pragma unroll
      for (int jj = 0; jj < 4; ++jj)
        vf[jj] = *(const short*)&buf[blk * 16 + kg * 4 + jj][h * 64 + dt * 16 + l15];
      f32x4 c = (f32x4)0.f;
      c = __builtin_amdgcn_mfma_f32_16x16x16bf16_1k(vf, pf, c, 0, 0, 0);
      short4v o;
#pragma unroll
      for (int r = 0; r < 4; ++r) o[r] = f2bf(c[r]);
      *(short4v*)&buf[blk * 16 + l15][h * 64 + dt * 16 + kg * 4] = o;
    }
  }

  __syncthreads();

  // ---- phase B: out = ctx @ w_out^T + b_out ----
  f32x4 acc[4][4];
#pragma unroll
  for (int i = 0; i < 4; ++i)
#pragma unroll
    for (int j = 0; j < 4; ++j) acc[i][j] = (f32x4)0.f;

#pragma unroll
  for (int kc = 0; kc < 16; ++kc) {
    short8 wf[4], cf[4];
#pragma unroll
    for (int ni = 0; ni < 4; ++ni)
      wf[ni] = *(const short8*)&woutb[(size_t)(w * 64 + ni * 16 + l15) * 512 +
                                      kc * 32 + kg * 8];
#pragma unroll
    for (int mi = 0; mi < 4; ++mi)
      cf[mi] = *(const short8*)&buf[mi * 16 + l15][kc * 32 + kg * 8];
#pragma unroll
    for (int mi = 0; mi < 4; ++mi)
#pragma unroll
      for (int ni = 0; ni < 4; ++ni)
        acc[mi][ni] = __builtin_amdgcn_mfma_f32_16x16x32_bf16(
            wf[ni], cf[mi], acc[mi][ni], 0, 0, 0);
  }

#pragma unroll
  for (int mi = 0; mi < 4; ++mi) {
    const size_t mrow = mbase + mi * 16 + l15;
#pragma unroll
    for (int ni = 0; ni < 4; ++ni) {
      const int nb = w * 64 + ni * 16 + kg * 4;
      f32x4 bv = *(const f32x4*)&b_out[nb];
      *(f32x4*)&out[mrow * 512 + nb] = acc[mi][ni] + bv;
    }
  }
}

// ---------------- launch ----------------
extern "C" void kernel_launch(void* const* d_in, const int* in_sizes, int n_in,
                              void* d_out, int out_size, void* d_ws, size_t ws_size,
                              hipStream_t stream) {
  (void)in_sizes; (void)n_in; (void)out_size; (void)ws_size;
  const float* x     = (const float*)d_in[0];
  const float* w_in  = (const float*)d_in[1];
  const float* b_in  = (const float*)d_in[2];
  const float* w_out = (const float*)d_in[3];
  const float* b_out = (const float*)d_in[4];
  float* out = (float*)d_out;

  char* ws = (char*)d_ws;
  bf16* qkv   = (bf16*)ws;                                   // 65536*1536 bf16 = 201 MB
  bf16* w2    = (bf16*)(ws + (size_t)65536 * 1536 * 2);     // packed w_in
  bf16* woutb = (bf16*)(ws + (size_t)65536 * 1536 * 2 + (size_t)786432 * 2);
  // x in bf16 lives in d_out (67 MB in a 134 MB buffer) — attn_out overwrites
  // d_out afterwards and never reads xb.
  bf16* xb = (bf16*)d_out;

  cvt_w_pack<<<384, 256, 0, stream>>>(w_in, w2);
  cvt_f32_to_bf16<<<256, 256, 0, stream>>>(w_out, woutb, 262144 / 4);
  cvt_f32_to_bf16<<<4096, 256, 0, stream>>>(x, xb, (65536 * 512) / 4);

  // QKV = xb @ w_in^T + b_in  (M=65536, N=1536, K=512), B direct from L2
  gemm_qkv<<<3072, 512, 0, stream>>>(xb, w2, b_in, qkv, 12);

  // fused: block attention + out = ctx @ w_out^T + b_out (fp32)
  attn_out_kernel<<<1024, 512, 0, stream>>>(qkv, woutb, b_out, out);
}

// Round 12
// 300.989 us; speedup vs baseline: 1.2737x; 1.1265x over previous
//
#include <hip/hip_runtime.h>
#include <hip/hip_bf16.h>

typedef __attribute__((ext_vector_type(4))) float f32x4;
typedef __attribute__((ext_vector_type(8))) short short8;
typedef __attribute__((ext_vector_type(4))) short short4v;
using bf16 = __hip_bfloat16;

__device__ __forceinline__ short f2bf(float x) {
  union { bf16 h; short s; } u;
  u.h = __float2bfloat16(x);
  return u.s;
}

__device__ __forceinline__ void gload16(const void* g, void* l) {
  __builtin_amdgcn_global_load_lds(
      (const __attribute__((address_space(1))) void*)g,
      (__attribute__((address_space(3))) void*)l, 16, 0, 0);
}

// ---------------- fp32 -> bf16 conversion (grid-stride) ----------------
__global__ void cvt_f32_to_bf16(const float* __restrict__ src,
                                bf16* __restrict__ dst, int n4) {
  int i = blockIdx.x * blockDim.x + threadIdx.x;
  const int stride = gridDim.x * blockDim.x;
  for (; i < n4; i += stride) {
    f32x4 v = ((const f32x4*)src)[i];
    short4v o;
    o[0] = f2bf(v[0]); o[1] = f2bf(v[1]); o[2] = f2bf(v[2]); o[3] = f2bf(v[3]);
    ((short4v*)dst)[i] = o;
  }
}

// ------- 256x128 GEMM, BK=64, 3-slot rotation: half the tile closes -------
// qkv = A @ B^T + bias (bf16 out). K=512 = 8 K-tiles of 64, fully unrolled.
// 512 threads = 8 waves (4M x 2N), wave tile 64x64, acc[4][4] + af[4][2] +
// bq[4][2] (~150 VGPR). LDS 144 KiB = 3 slots x (A 256x64 + B 128x64) bf16
// -> 1 block/CU (occupancy proven non-binding at this plateau, r4 vs r8).
//
// Rationale: m233 shows the per-tile close (stage+vmcnt+barrier) dominates
// the 2-phase critical path; BK=64 halves the close count (8 vs 16) at
// identical per-K LDS/MFMA volume, keeping the r4/r8-proven ledger:
//   - during tile t stage tile t+2 into slot (t+2)%3 == (t-1)%3 (that
//     slot's last ds_reads completed before the close-of-(t-1) barrier);
//   - close of tile t: counted vmcnt(6) retires tile t+1's 6 loads ->
//     t+1 fully resident. Tail: V(0) @ t=6; t=7 falls to epilogue.
//
// LDS swizzle for 128B rows (3-bit key): LDS[row][slot] = global[row][slot ^
// ((row>>1)&7)], slots = 8 x 16B per row. Read side XORs the same key ->
// 16 lanes spread over 8 granule classes, 2 lanes each = 2-way = free.
// Staged via linear-dest gload16 + pre-swizzled SOURCE col (rule #21).
__global__ __launch_bounds__(512) void gemm_qkv(
    const bf16* __restrict__ A,          // xb [65536][512]
    const bf16* __restrict__ B,          // w_in bf16 [1536][512]
    const float* __restrict__ bias,
    bf16* __restrict__ C, int nbx)       // qkv, ldc = 1536
{
  __shared__ __align__(16) bf16 lA[3][256 * 64];
  __shared__ __align__(16) bf16 lB[3][128 * 64];

  const int tid  = threadIdx.x;
  const int lane = tid & 63;
  const int w    = tid >> 6;   // wave 0..7
  const int mr   = w & 3;      // M quarter: rows mr*64..+63
  const int wn   = w >> 2;     // N half:    cols wn*64..+63
  const int l15  = lane & 15;
  const int kg   = lane >> 4;         // k 16B-slot sub-index 0..3
  const int rx   = (l15 >> 1) & 7;    // read-side swizzle key

  const int nwg = gridDim.x;
  const int dd  = blockIdx.x;
  const int wid = (dd & 7) * (nwg >> 3) + (dd >> 3);  // bijective XCD swizzle
  const size_t bm = (size_t)(wid / nbx) * 256;
  const size_t bn = (size_t)(wid % nbx) * 128;

  // Staging: round covers 64 rows; thread -> row (tid>>3), slot (tid&7);
  // source col-slot pre-swizzled with key ((tid>>4)&7) == ((row>>1)&7).
  const int srow = tid >> 3;
  const int scol = ((tid & 7) ^ ((tid >> 4) & 7)) * 8;

  const bf16* Ab = A + (bm + srow) * 512 + scol;
  const bf16* Bb = B + (bn + srow) * 512 + scol;

  f32x4 acc[4][4];
#pragma unroll
  for (int i = 0; i < 4; ++i)
#pragma unroll
    for (int j = 0; j < 4; ++j) acc[i][j] = (f32x4)0.f;

  short8 af[4][2], bq[4][2];

  // one K-tile of A = 4 rounds of 64 rows; B = 2 rounds
#define STGA(buf, kt) do { \
    gload16(Ab + (size_t)(kt),             &lA[buf][tid * 8]); \
    gload16(Ab + (size_t) 64 * 512 + (kt), &lA[buf][ 4096 + tid * 8]); \
    gload16(Ab + (size_t)128 * 512 + (kt), &lA[buf][ 8192 + tid * 8]); \
    gload16(Ab + (size_t)192 * 512 + (kt), &lA[buf][12288 + tid * 8]); } while (0)
#define STGB(buf, kt) do { \
    gload16(Bb + (size_t)(kt),             &lB[buf][tid * 8]); \
    gload16(Bb + (size_t) 64 * 512 + (kt), &lB[buf][ 4096 + tid * 8]); } while (0)

#define CLOSE_V(N) do { \
    __builtin_amdgcn_sched_barrier(0); \
    asm volatile("s_waitcnt vmcnt(" #N ")" ::: "memory"); \
    __builtin_amdgcn_sched_barrier(0); \
    __builtin_amdgcn_s_barrier(); \
    __builtin_amdgcn_sched_barrier(0); \
    asm volatile("" ::: "memory"); } while (0)

  // prologue: stage tiles 0,1 (6 loads each); V(6) -> tile 0 resident
  STGA(0, 0);  STGB(0, 0);
  STGA(1, 64); STGB(1, 64);
  CLOSE_V(6);

#pragma unroll
  for (int t = 0; t < 8; ++t) {
    const int cur = t % 3;
    const int pf  = (t + 2) % 3;
    const int kt2 = (t + 2) * 64;

    // fragment reads from the stable current slot (16 x ds_read_b128)
#pragma unroll
    for (int mi = 0; mi < 4; ++mi)
#pragma unroll
      for (int ks = 0; ks < 2; ++ks)
        af[mi][ks] = *(const short8*)
            &lA[cur][(mr * 64 + mi * 16 + l15) * 64 + ((ks * 4 + kg) ^ rx) * 8];
#pragma unroll
    for (int ni = 0; ni < 4; ++ni)
#pragma unroll
      for (int ks = 0; ks < 2; ++ks)
        bq[ni][ks] = *(const short8*)
            &lB[cur][(wn * 64 + ni * 16 + l15) * 64 + ((ks * 4 + kg) ^ rx) * 8];

    // stage tile t+2 (slot last read during t-1, barrier-separated)
    if (t < 6) STGA(pf, kt2);

    __builtin_amdgcn_s_setprio(1);
#pragma unroll
    for (int mi = 0; mi < 4; ++mi)
#pragma unroll
      for (int ni = 0; ni < 4; ++ni)
        acc[mi][ni] = __builtin_amdgcn_mfma_f32_16x16x32_bf16(
            bq[ni][0], af[mi][0], acc[mi][ni], 0, 0, 0);
    __builtin_amdgcn_s_setprio(0);

    if (t < 6) STGB(pf, kt2);

    __builtin_amdgcn_s_setprio(1);
#pragma unroll
    for (int mi = 0; mi < 4; ++mi)
#pragma unroll
      for (int ni = 0; ni < 4; ++ni)
        acc[mi][ni] = __builtin_amdgcn_mfma_f32_16x16x32_bf16(
            bq[ni][1], af[mi][1], acc[mi][ni], 0, 0, 0);
    __builtin_amdgcn_s_setprio(0);

    if (t <= 5)      CLOSE_V(6);
    else if (t == 6) CLOSE_V(0);
    // t == 7: fall through to epilogue
  }

#undef STGA
#undef STGB
#undef CLOSE_V

  // Epilogue: lane holds m = bm+mr*64+mi*16+l15, n = bn+wn*64+ni*16+kg*4+j
#pragma unroll
  for (int mi = 0; mi < 4; ++mi) {
    const size_t mrow = bm + mr * 64 + mi * 16 + l15;
#pragma unroll
    for (int ni = 0; ni < 4; ++ni) {
      const int nb = (int)bn + wn * 64 + ni * 16 + kg * 4;
      f32x4 bv = *(const f32x4*)&bias[nb];
      f32x4 r = acc[mi][ni] + bv;
      short4v o;
      o[0] = f2bf(r[0]); o[1] = f2bf(r[1]); o[2] = f2bf(r[2]); o[3] = f2bf(r[3]);
      *(short4v*)(C + mrow * 1536 + nb) = o;
    }
  }
}

// ------------- fused block-attention + output GEMM (r9, passing) -------------
__global__ __launch_bounds__(512) void attn_out_kernel(
    const bf16* __restrict__ qkv, const bf16* __restrict__ woutb,
    const float* __restrict__ b_out, float* __restrict__ out)
{
  __shared__ __align__(16) bf16 buf[64][520];

  const int tid  = threadIdx.x;
  const int w    = tid >> 6;
  const int lane = tid & 63;
  const int l15  = lane & 15;
  const int kg   = lane >> 4;
  const size_t mbase = (size_t)blockIdx.x * 64;
  const int blk = w >> 1;
  const size_t rbase = mbase + blk * 16;

  // ---- stage V strip: wave w stages rows w*8..+7, 1024B per row ----
  {
    const bf16* vsrc = qkv + 1024 + (size_t)lane * 8;
#pragma unroll
    for (int i = 0; i < 8; ++i) {
      const int row = w * 8 + i;
      gload16(vsrc + (mbase + row) * 1536, &buf[row][0]);
    }
  }
  __syncthreads();

  // ---- phase A: attention, 4 heads per wave; ctx overwrites own V ----
#pragma unroll
  for (int hi = 0; hi < 4; ++hi) {
    const int h = (w & 1) * 4 + hi;
    const bf16* qp = qkv + (rbase + l15) * 1536 + h * 64 + kg * 8;
    short8 qf0 = *(const short8*)qp;
    short8 qf1 = *(const short8*)(qp + 32);
    short8 kf0 = *(const short8*)(qp + 512);
    short8 kf1 = *(const short8*)(qp + 544);

    f32x4 st = (f32x4)0.f;
    st = __builtin_amdgcn_mfma_f32_16x16x32_bf16(kf0, qf0, st, 0, 0, 0);
    st = __builtin_amdgcn_mfma_f32_16x16x32_bf16(kf1, qf1, st, 0, 0, 0);

    float s[4];
#pragma unroll
    for (int r = 0; r < 4; ++r) s[r] = st[r] * 0.125f;
    float mx = fmaxf(fmaxf(s[0], s[1]), fmaxf(s[2], s[3]));
    mx = fmaxf(mx, __shfl_xor(mx, 16));
    mx = fmaxf(mx, __shfl_xor(mx, 32));
    float p[4], sum = 0.f;
#pragma unroll
    for (int r = 0; r < 4; ++r) { p[r] = __expf(s[r] - mx); sum += p[r]; }
    sum += __shfl_xor(sum, 16);
    sum += __shfl_xor(sum, 32);
    const float inv = 1.f / sum;

    short4v pf;
#pragma unroll
    for (int r = 0; r < 4; ++r) pf[r] = f2bf(p[r] * inv);

#pragma unroll
    for (int dt = 0; dt < 4; ++dt) {
      short4v vf;
#pragma unroll
      for (int jj = 0; jj < 4; ++jj)
        vf[jj] = *(const short*)&buf[blk * 16 + kg * 4 + jj][h * 64 + dt * 16 + l15];
      f32x4 c = (f32x4)0.f;
      c = __builtin_amdgcn_mfma_f32_16x16x16bf16_1k(vf, pf, c, 0, 0, 0);
      short4v o;
#pragma unroll
      for (int r = 0; r < 4; ++r) o[r] = f2bf(c[r]);
      *(short4v*)&buf[blk * 16 + l15][h * 64 + dt * 16 + kg * 4] = o;
    }
  }

  __syncthreads();

  // ---- phase B: out = ctx @ w_out^T + b_out ----
  f32x4 acc[4][4];
#pragma unroll
  for (int i = 0; i < 4; ++i)
#pragma unroll
    for (int j = 0; j < 4; ++j) acc[i][j] = (f32x4)0.f;

#pragma unroll
  for (int kc = 0; kc < 16; ++kc) {
    short8 wf[4], cf[4];
#pragma unroll
    for (int ni = 0; ni < 4; ++ni)
      wf[ni] = *(const short8*)&woutb[(size_t)(w * 64 + ni * 16 + l15) * 512 +
                                      kc * 32 + kg * 8];
#pragma unroll
    for (int mi = 0; mi < 4; ++mi)
      cf[mi] = *(const short8*)&buf[mi * 16 + l15][kc * 32 + kg * 8];
#pragma unroll
    for (int mi = 0; mi < 4; ++mi)
#pragma unroll
      for (int ni = 0; ni < 4; ++ni)
        acc[mi][ni] = __builtin_amdgcn_mfma_f32_16x16x32_bf16(
            wf[ni], cf[mi], acc[mi][ni], 0, 0, 0);
  }

#pragma unroll
  for (int mi = 0; mi < 4; ++mi) {
    const size_t mrow = mbase + mi * 16 + l15;
#pragma unroll
    for (int ni = 0; ni < 4; ++ni) {
      const int nb = w * 64 + ni * 16 + kg * 4;
      f32x4 bv = *(const f32x4*)&b_out[nb];
      *(f32x4*)&out[mrow * 512 + nb] = acc[mi][ni] + bv;
    }
  }
}

// ---------------- launch ----------------
extern "C" void kernel_launch(void* const* d_in, const int* in_sizes, int n_in,
                              void* d_out, int out_size, void* d_ws, size_t ws_size,
                              hipStream_t stream) {
  (void)in_sizes; (void)n_in; (void)out_size; (void)ws_size;
  const float* x     = (const float*)d_in[0];
  const float* w_in  = (const float*)d_in[1];
  const float* b_in  = (const float*)d_in[2];
  const float* w_out = (const float*)d_in[3];
  const float* b_out = (const float*)d_in[4];
  float* out = (float*)d_out;

  char* ws = (char*)d_ws;
  bf16* qkv   = (bf16*)ws;                                   // 65536*1536 bf16 = 201 MB
  bf16* winb  = (bf16*)(ws + (size_t)65536 * 1536 * 2);      // 1536*512
  bf16* woutb = (bf16*)(ws + (size_t)65536 * 1536 * 2 + (size_t)786432 * 2);
  // x in bf16 lives in d_out (67 MB in a 134 MB buffer) — attn_out overwrites
  // d_out afterwards and never reads xb.
  bf16* xb = (bf16*)d_out;

  cvt_f32_to_bf16<<<768, 256, 0, stream>>>(w_in, winb, 786432 / 4);
  cvt_f32_to_bf16<<<256, 256, 0, stream>>>(w_out, woutb, 262144 / 4);
  cvt_f32_to_bf16<<<4096, 256, 0, stream>>>(x, xb, (65536 * 512) / 4);

  // QKV = xb @ w_in^T + b_in  (M=65536, N=1536, K=512), BK=64, 8 closes
  gemm_qkv<<<3072, 512, 0, stream>>>(xb, winb, b_in, qkv, 12);

  // fused: block attention + out = ctx @ w_out^T + b_out (fp32)
  attn_out_kernel<<<1024, 512, 0, stream>>>(qkv, woutb, b_out, out);
}